// Round 1
// 272.126 us; speedup vs baseline: 1.0530x; 1.0530x over previous
//
#include <hip/hip_runtime.h>
#include <stdint.h>

// Problem constants
#define BB   256
#define NN   2048
#define MM   64
#define CC   512
#define OUTD 198

typedef float vf4 __attribute__((ext_vector_type(4)));

__device__ __forceinline__ float softplusf(float x) {
    return x > 20.f ? x : log1pf(expf(x));
}
__device__ __forceinline__ float sigmoidf(float x) {
    return 1.f / (1.f + expf(-x));
}

// ---------------------------------------------------------------------------
// Fully fused NTM write head: one block per batch, 1024 threads (16 waves).
// Phases within a block (LDS carries all intermediates, zero global
// round-trips for logits / w_g / w):
//   0: controller matvec o = W @ h_b + b  (4 lanes/row, shuffle reduce)
//   0b: activations -> k,e,a,scalars,||k||
//   1: content logits (16 lanes/row, float4 loads, xor-shuffle reduce)
//   2: softmax -> gate -> circular shift -> sharpen -> normalize -> w
//   3: mem_new = memory*(1-w*e)+w*a  (re-read is LLC-hot from phase 1;
//      nontemporal stores keep the output stream from evicting it)
// No global barriers: blocks pipeline through phases independently, so HBM
// never drains between stages (the old 4-kernel structure drained 3 times).
// ---------------------------------------------------------------------------
__global__ __launch_bounds__(1024, 4) void k_fused(
        const float* __restrict__ h, const float* __restrict__ Wm,
        const float* __restrict__ bias, const float* __restrict__ w_prev,
        const float* __restrict__ mem, float* __restrict__ w_out,
        float* __restrict__ mem_out) {
    __shared__ float hs[CC];
    __shared__ float os[OUTD];
    __shared__ __align__(16) float kk[MM];   // k + 1e-16
    __shared__ __align__(16) float ee[MM];   // sigmoid(e)
    __shared__ __align__(16) float aa[MM];
    __shared__ float sc[8];                  // 0:beta 1:g 2:gamma 3:knorm 4..6:s
    __shared__ float lg[NN];                 // logits, later final w
    __shared__ float wg[NN];                 // gated weights
    __shared__ float red[16];

    const int b = blockIdx.x;
    const int t = threadIdx.x;
    const int lane = t & 63;
    const int wid = t >> 6;

    // ---- phase 0: controller projection (198x512 matvec) -----------------
    if (t < CC) hs[t] = h[(size_t)b * CC + t];
    __syncthreads();

    if (t < 4 * OUTD) {                      // 4 lanes per output row
        const int row = t >> 2, l4 = t & 3;
        const float* wr = Wm + (size_t)row * CC + 4 * l4;
        float acc = 0.f;
        #pragma unroll
        for (int c = 0; c < CC; c += 16) {
            const float4 p = *(const float4*)(wr + c);
            const int hb = c + 4 * l4;
            acc += p.x * hs[hb] + p.y * hs[hb + 1] + p.z * hs[hb + 2] + p.w * hs[hb + 3];
        }
        acc += __shfl_xor(acc, 1, 64);
        acc += __shfl_xor(acc, 2, 64);
        if (l4 == 0) os[row] = acc + bias[row];
    }
    __syncthreads();

    // ---- phase 0b: split + activations -----------------------------------
    if (t < 64) {
        const float kv = os[t] + 1e-16f;
        kk[t] = kv;
        float ss = kv * kv;
        #pragma unroll
        for (int off = 32; off; off >>= 1) ss += __shfl_xor(ss, off, 64);
        if (t == 0) sc[3] = sqrtf(ss);       // ||k + 1e-16||
    } else if (t < 128) {
        const int m = t - 64;
        ee[m] = sigmoidf(os[70 + m]);
        aa[m] = os[134 + m];
    } else if (t == 128) {
        sc[0] = softplusf(os[64]);           // beta
    } else if (t == 129) {
        sc[1] = sigmoidf(os[65]);            // g
    } else if (t == 130) {
        sc[2] = 1.f + softplusf(os[69]);     // gamma
    } else if (t == 131) {                   // 3-way softmax for shift weights
        const float x0 = os[66], x1 = os[67], x2 = os[68];
        const float mx = fmaxf(x0, fmaxf(x1, x2));
        const float e0 = expf(x0 - mx), e1 = expf(x1 - mx), e2 = expf(x2 - mx);
        const float inv = 1.f / (e0 + e1 + e2);
        sc[4] = e0 * inv; sc[5] = e1 * inv; sc[6] = e2 * inv;
    }
    __syncthreads();

    // ---- phase 1: content-addressing logits ------------------------------
    {
        const int l = t & 15, grp = t >> 4;  // 64 groups of 16 lanes
        const float kv0 = kk[4 * l + 0], kv1 = kk[4 * l + 1];
        const float kv2 = kk[4 * l + 2], kv3 = kk[4 * l + 3];
        const float beta = sc[0], knorm = sc[3];
        const float* mb = mem + (size_t)b * NN * MM;
        #pragma unroll 4
        for (int it = 0; it < 32; ++it) {
            const int row = it * 64 + grp;   // wave reads 4 consecutive rows = 1KB
            const float4 p = *(const float4*)(mb + (size_t)row * MM + 4 * l);
            const float m0 = p.x + 1e-16f, m1 = p.y + 1e-16f;
            const float m2 = p.z + 1e-16f, m3 = p.w + 1e-16f;
            float dot = m0 * kv0 + m1 * kv1 + m2 * kv2 + m3 * kv3;
            float ss  = m0 * m0 + m1 * m1 + m2 * m2 + m3 * m3;
            #pragma unroll
            for (int off = 1; off < 16; off <<= 1) {
                dot += __shfl_xor(dot, off, 64);
                ss  += __shfl_xor(ss,  off, 64);
            }
            if (l == 0)
                lg[row] = beta * dot / fmaxf(sqrtf(ss) * knorm, 1e-8f);
        }
    }
    __syncthreads();

    // ---- phase 2: softmax -> gate -> shift -> sharpen -> normalize -------
    const float g = sc[1], gamma = sc[2];
    const float s0 = sc[4], s1 = sc[5], s2 = sc[6];

    float v0 = lg[t], v1 = lg[t + 1024];
    float lmax = fmaxf(v0, v1);
    #pragma unroll
    for (int off = 32; off; off >>= 1) lmax = fmaxf(lmax, __shfl_xor(lmax, off, 64));
    if (lane == 0) red[wid] = lmax;
    __syncthreads();
    float mx = red[0];
    #pragma unroll
    for (int i = 1; i < 16; ++i) mx = fmaxf(mx, red[i]);
    __syncthreads();

    v0 = expf(v0 - mx); v1 = expf(v1 - mx);
    float lsum = v0 + v1;
    #pragma unroll
    for (int off = 32; off; off >>= 1) lsum += __shfl_xor(lsum, off, 64);
    if (lane == 0) red[wid] = lsum;
    __syncthreads();
    float tot = 0.f;
    #pragma unroll
    for (int i = 0; i < 16; ++i) tot += red[i];
    __syncthreads();
    const float inv = 1.f / tot;

    wg[t]        = g * (v0 * inv) + (1.f - g) * w_prev[(size_t)b * NN + t];
    wg[t + 1024] = g * (v1 * inv) + (1.f - g) * w_prev[(size_t)b * NN + t + 1024];
    __syncthreads();

    float ws0, ws1;
    {
        const int n0 = t;
        const float wt0 = wg[(n0 + NN - 1) & (NN - 1)] * s0 + wg[n0] * s1
                        + wg[(n0 + 1) & (NN - 1)] * s2;
        ws0 = (wt0 > 0.f) ? exp2f(gamma * log2f(wt0)) : 0.f;
        const int n1 = t + 1024;
        const float wt1 = wg[(n1 - 1) & (NN - 1)] * s0 + wg[n1] * s1
                        + wg[(n1 + 1) & (NN - 1)] * s2;
        ws1 = (wt1 > 0.f) ? exp2f(gamma * log2f(wt1)) : 0.f;
    }
    float psum = ws0 + ws1;
    #pragma unroll
    for (int off = 32; off; off >>= 1) psum += __shfl_xor(psum, off, 64);
    if (lane == 0) red[wid] = psum;
    __syncthreads();
    float ptot = 0.f;
    #pragma unroll
    for (int i = 0; i < 16; ++i) ptot += red[i];
    const float invp = 1.f / (ptot + 1e-16f);

    const float wf0 = ws0 * invp, wf1 = ws1 * invp;
    lg[t] = wf0;                              // reuse lg as final-w buffer
    lg[t + 1024] = wf1;
    w_out[(size_t)b * NN + t] = wf0;
    w_out[(size_t)b * NN + t + 1024] = wf1;
    __syncthreads();

    // ---- phase 3: erase/add memory write ---------------------------------
    {
        const int m0 = (4 * t) & 63;          // fixed per thread across iters
        const vf4 ev = *(const vf4*)(ee + m0);
        const vf4 av = *(const vf4*)(aa + m0);
        const float* mb = mem + (size_t)b * NN * MM + 4 * t;
        float* ob = mem_out + (size_t)b * NN * MM + 4 * t;
        #pragma unroll 8
        for (int it = 0; it < 32; ++it) {
            const float w = lg[it * 64 + (t >> 4)];   // LDS broadcast
            const float4 p = *(const float4*)(mb + it * 4096);
            vf4 o;
            o.x = p.x * (1.f - w * ev.x) + w * av.x;
            o.y = p.y * (1.f - w * ev.y) + w * av.y;
            o.z = p.z * (1.f - w * ev.z) + w * av.z;
            o.w = p.w * (1.f - w * ev.w) + w * av.w;
            __builtin_nontemporal_store(o, (vf4*)(ob + it * 4096));
        }
    }
}

extern "C" void kernel_launch(void* const* d_in, const int* in_sizes, int n_in,
                              void* d_out, int out_size, void* d_ws, size_t ws_size,
                              hipStream_t stream) {
    const float* h      = (const float*)d_in[0];
    const float* w_prev = (const float*)d_in[1];
    const float* memory = (const float*)d_in[2];
    const float* W      = (const float*)d_in[3];
    const float* bias   = (const float*)d_in[4];
    float* out = (float*)d_out;

    float* w_out   = out;                       // [B,N]
    float* mem_out = out + (size_t)BB * NN;     // [B,N,M]

    k_fused<<<BB, 1024, 0, stream>>>(h, W, bias, w_prev, memory, w_out, mem_out);
}